// Round 1
// 93.237 us; speedup vs baseline: 1.0156x; 1.0156x over previous
//
#include <hip/hip_runtime.h>

// ChannelAttention b=2, n=4096, c=32 fp32.
// S = X X^T (Gram), softmax over j per row i, out[j,c] = sum_i attn[i,j] x[i,c]; out*g + x.
//
// MFMA plan (16x16x32 f16, K = c = 32):
//  k0: convert x -> Xf16 [b][n][c] and XT f16 [b][c][n]  (ws)
//  k1: Z_i = sum_j exp(s_ij - 48); store c2[i] = -log2(Z_i) - 48*log2e
//  k2: per 16-j tile: loop i: S-MFMA -> attn=exp2(s*log2e + c2[i]) (fp16)
//      -> in-register quad shuffle (C-layout -> A-layout) -> PV-MFMA.
//
// R3 -> R4 (theory: latency-chain bound, ~8% issue utilization):
//  * k2: LDS round-trip (ds_write x2 + ds_read + 2x lgkmcnt drains, ~200-250cy
//    serial per iter) replaced by 8x ds_bpermute + 4x cndmask in registers.
//    The C->A transpose only crosses quads at fixed lane&15, so it's a static
//    permutation. cvt_pkrtz fuses f32->f16 convert+pack (1 op vs 3).
//  * k1: 1-deep prefetch of the 4 B-fragments (was: loads fed MFMA directly,
//    exposing full L2 latency each iteration).
//  * __launch_bounds__(512,4) pins VGPR<=128 -> guaranteed 2 blocks/CU.

typedef _Float16 half8 __attribute__((ext_vector_type(8)));
typedef _Float16 half4v __attribute__((ext_vector_type(4)));
typedef _Float16 half2v __attribute__((ext_vector_type(2)));
typedef float float4v __attribute__((ext_vector_type(4)));
typedef int int4v __attribute__((ext_vector_type(4)));

#define NN 4096
#define CC 32
#define L2E 1.44269504f
#define SHIFT 48.0f

// ---------------- k0: fp32 -> fp16 row-major + fp16 transposed ----------------
__global__ __launch_bounds__(256) void k_convert(const float* __restrict__ x,
                                                 _Float16* __restrict__ xf,
                                                 _Float16* __restrict__ xt) {
    const int t = blockIdx.x * 256 + threadIdx.x;   // 65536 threads
    const int n  = t & 4095;
    const int cg = (t >> 12) & 7;
    const int b  = t >> 15;
    const int row = (b << 12) | n;
    const float4* src = (const float4*)(x + (size_t)row * CC + cg * 4);
    float4 v = *src;
    _Float16 h0 = (_Float16)v.x, h1 = (_Float16)v.y, h2 = (_Float16)v.z, h3 = (_Float16)v.w;
    *(half4v*)(xf + (size_t)row * CC + cg * 4) = (half4v){h0, h1, h2, h3};
    _Float16* xtb = xt + (size_t)b * CC * NN;
    xtb[(cg * 4 + 0) * NN + n] = h0;   // consecutive lanes -> consecutive n: coalesced
    xtb[(cg * 4 + 1) * NN + n] = h1;
    xtb[(cg * 4 + 2) * NN + n] = h2;
    xtb[(cg * 4 + 3) * NN + n] = h3;
}

// ---------------- k1: per-row shifted sum-of-exp -> c2[i] ----------------
// Block = 512 threads (8 waves), one 16-row i-tile; each wave covers 512 j's,
// 4 independent B-tiles per iteration, 1-deep prefetch of the next 4 B-tiles.
__global__ __launch_bounds__(512, 4) void k_pass1(const _Float16* __restrict__ xf,
                                                  float* __restrict__ c2out) {
    const int tid = threadIdx.x;
    const int wave = tid >> 6, lane = tid & 63;
    const int quad = lane >> 4, l15 = lane & 15;
    const int b = blockIdx.x >> 8;
    const int i0 = (blockIdx.x & 255) * 16;
    const _Float16* xb = xf + (size_t)b * NN * CC;

    const half8 afrag = *(const half8*)(xb + (size_t)(i0 + l15) * CC + quad * 8);
    const float4v zf = {0.f, 0.f, 0.f, 0.f};
    float z[4] = {0.f, 0.f, 0.f, 0.f};
    const float c2c = -SHIFT * L2E;

    const int jbase = wave * 512;
    // prologue: tile 0 loads
    half8 b0 = *(const half8*)(xb + (size_t)(jbase + l15) * CC + quad * 8);
    half8 b1 = *(const half8*)(xb + (size_t)(jbase + 16 + l15) * CC + quad * 8);
    half8 b2 = *(const half8*)(xb + (size_t)(jbase + 32 + l15) * CC + quad * 8);
    half8 b3 = *(const half8*)(xb + (size_t)(jbase + 48 + l15) * CC + quad * 8);

    for (int jt = 0; jt < 8; ++jt) {           // 8 iters x 4 tiles x 16 j = 512 j
        const int jn = jbase + ((jt + 1) & 7) * 64;   // wraps on last iter (harmless)
        half8 n0 = *(const half8*)(xb + (size_t)(jn + l15) * CC + quad * 8);
        half8 n1 = *(const half8*)(xb + (size_t)(jn + 16 + l15) * CC + quad * 8);
        half8 n2 = *(const half8*)(xb + (size_t)(jn + 32 + l15) * CC + quad * 8);
        half8 n3 = *(const half8*)(xb + (size_t)(jn + 48 + l15) * CC + quad * 8);

        float4v s0 = __builtin_amdgcn_mfma_f32_16x16x32_f16(afrag, b0, zf, 0, 0, 0);
        float4v s1 = __builtin_amdgcn_mfma_f32_16x16x32_f16(afrag, b1, zf, 0, 0, 0);
        float4v s2 = __builtin_amdgcn_mfma_f32_16x16x32_f16(afrag, b2, zf, 0, 0, 0);
        float4v s3 = __builtin_amdgcn_mfma_f32_16x16x32_f16(afrag, b3, zf, 0, 0, 0);
#pragma unroll
        for (int r = 0; r < 4; ++r) {
            z[r] += __builtin_amdgcn_exp2f(fmaf(s0[r], L2E, c2c));
            z[r] += __builtin_amdgcn_exp2f(fmaf(s1[r], L2E, c2c));
            z[r] += __builtin_amdgcn_exp2f(fmaf(s2[r], L2E, c2c));
            z[r] += __builtin_amdgcn_exp2f(fmaf(s3[r], L2E, c2c));
        }
        b0 = n0; b1 = n1; b2 = n2; b3 = n3;
    }
    // combine over the 16 j-lanes within each quad group
#pragma unroll
    for (int off = 1; off <= 8; off <<= 1) {
#pragma unroll
        for (int r = 0; r < 4; ++r) z[r] += __shfl_xor(z[r], off, 64);
    }
    __shared__ float zw[8][16];
    if (l15 == 0) {
#pragma unroll
        for (int r = 0; r < 4; ++r) zw[wave][quad * 4 + r] = z[r];
    }
    __syncthreads();
    if (tid < 16) {
        float zs = 0.f;
#pragma unroll
        for (int w = 0; w < 8; ++w) zs += zw[w][tid];
        c2out[b * NN + i0 + tid] = -(__builtin_amdgcn_logf(zs) + SHIFT * L2E);
    }
}

// ---------------- k2: output pass ----------------
// Block = 512 threads (8 waves), one 16-j tile; wave w covers i in [w*512,(w+1)*512),
// 32 i per iteration (16 iters). P tile's C-layout -> A-layout transpose done fully
// in registers: target lane (q,j15) needs P[i32=8q+t][j15], held by source lanes
// {j15, j15+16} (p0) / {j15+32, j15+48} (p1 source-quad pairs) -> 8x ds_bpermute
// with two static byte-address registers + 4x cndmask on lane<32.
__global__ __launch_bounds__(512, 4) void k_pass2(const _Float16* __restrict__ xf,
                                                  const _Float16* __restrict__ xt,
                                                  const float* __restrict__ c2,
                                                  const float* __restrict__ x,
                                                  const float* __restrict__ gamma,
                                                  float* __restrict__ out) {
    const int tid = threadIdx.x;
    const int wave = tid >> 6, lane = tid & 63;
    const int quad = lane >> 4, l15 = lane & 15;
    const int b = blockIdx.x >> 8;
    const int j0 = (blockIdx.x & 255) * 16;
    const _Float16* xb  = xf + (size_t)b * NN * CC;
    const _Float16* xtb = xt + (size_t)b * CC * NN;
    const float* c2b = c2 + b * NN;

    __shared__ float red[8][16][32];

    // bpermute byte addresses: A0/A1 pull from lane ((q&1)*32 + j15),
    // A2/A3 from lane ((q&1)*32 + 16 + j15). Select p0 (q<2) vs p1 (q>=2) data.
    const int addrLo = (((quad & 1) << 5) + l15) << 2;
    const int addrHi = addrLo + 64;
    const bool lo32 = (lane < 32);

    const half8 bjfrag = *(const half8*)(xb + (size_t)(j0 + l15) * CC + quad * 8);
    const float4v zf = {0.f, 0.f, 0.f, 0.f};
    float4v acc0 = zf, acc1 = zf;

    const int ibase = wave * 512;
    // prologue loads (iteration 0)
    half8 a0  = *(const half8*)(xb + (size_t)(ibase + l15) * CC + quad * 8);
    half8 a1  = *(const half8*)(xb + (size_t)(ibase + 16 + l15) * CC + quad * 8);
    half8 xb0 = *(const half8*)(xtb + (size_t)l15 * NN + ibase + quad * 8);
    half8 xb1 = *(const half8*)(xtb + (size_t)(l15 + 16) * NN + ibase + quad * 8);
    float4v c20 = *(const float4v*)(c2b + ibase + quad * 4);
    float4v c21 = *(const float4v*)(c2b + ibase + 16 + quad * 4);

    for (int it = 0; it < 16; ++it) {
        // prefetch next iteration (wraps to iter 0's addresses on the last — harmless)
        const int inx = ibase + ((it + 1) & 15) * 32;
        half8 na0  = *(const half8*)(xb + (size_t)(inx + l15) * CC + quad * 8);
        half8 na1  = *(const half8*)(xb + (size_t)(inx + 16 + l15) * CC + quad * 8);
        half8 nxb0 = *(const half8*)(xtb + (size_t)l15 * NN + inx + quad * 8);
        half8 nxb1 = *(const half8*)(xtb + (size_t)(l15 + 16) * NN + inx + quad * 8);
        float4v nc20 = *(const float4v*)(c2b + inx + quad * 4);
        float4v nc21 = *(const float4v*)(c2b + inx + 16 + quad * 4);

        float4v s0 = __builtin_amdgcn_mfma_f32_16x16x32_f16(a0, bjfrag, zf, 0, 0, 0);
        float4v s1 = __builtin_amdgcn_mfma_f32_16x16x32_f16(a1, bjfrag, zf, 0, 0, 0);
        float4v e0, e1;
#pragma unroll
        for (int r = 0; r < 4; ++r) {
            e0[r] = __builtin_amdgcn_exp2f(fmaf(s0[r], L2E, c20[r]));
            e1[r] = __builtin_amdgcn_exp2f(fmaf(s1[r], L2E, c21[r]));
        }
        // p0 regs {0,1},{2,3} -> d0,d1 ; p1 -> d2,d3 (cvt+pack fused, RTZ)
        const int d0 = __builtin_bit_cast(int, (half2v)__builtin_amdgcn_cvt_pkrtz(e0[0], e0[1]));
        const int d1 = __builtin_bit_cast(int, (half2v)__builtin_amdgcn_cvt_pkrtz(e0[2], e0[3]));
        const int d2 = __builtin_bit_cast(int, (half2v)__builtin_amdgcn_cvt_pkrtz(e1[0], e1[1]));
        const int d3 = __builtin_bit_cast(int, (half2v)__builtin_amdgcn_cvt_pkrtz(e1[2], e1[3]));
        // in-register C-layout -> A-layout quad shuffle (all lanes active)
        const int q0 = __builtin_amdgcn_ds_bpermute(addrLo, d0);
        const int q1 = __builtin_amdgcn_ds_bpermute(addrLo, d1);
        const int q2 = __builtin_amdgcn_ds_bpermute(addrHi, d0);
        const int q3 = __builtin_amdgcn_ds_bpermute(addrHi, d1);
        const int q4 = __builtin_amdgcn_ds_bpermute(addrLo, d2);
        const int q5 = __builtin_amdgcn_ds_bpermute(addrLo, d3);
        const int q6 = __builtin_amdgcn_ds_bpermute(addrHi, d2);
        const int q7 = __builtin_amdgcn_ds_bpermute(addrHi, d3);
        int4v ai;
        ai[0] = lo32 ? q0 : q4;
        ai[1] = lo32 ? q1 : q5;
        ai[2] = lo32 ? q2 : q6;
        ai[3] = lo32 ? q3 : q7;
        const half8 a2 = __builtin_bit_cast(half8, ai);   // P^T[j=l15][i32=quad*8+t]

        acc0 = __builtin_amdgcn_mfma_f32_16x16x32_f16(a2, xb0, acc0, 0, 0, 0);
        acc1 = __builtin_amdgcn_mfma_f32_16x16x32_f16(a2, xb1, acc1, 0, 0, 0);

        a0 = na0; a1 = na1; xb0 = nxb0; xb1 = nxb1; c20 = nc20; c21 = nc21;
    }

    // block reduction across the 8 waves
#pragma unroll
    for (int r = 0; r < 4; ++r) {
        red[wave][quad * 4 + r][l15]      = acc0[r];
        red[wave][quad * 4 + r][l15 + 16] = acc1[r];
    }
    __syncthreads();
    {
        const int jj = tid >> 5, c = tid & 31;   // 512 threads = 16 j x 32 c
        float s = 0.f;
#pragma unroll
        for (int w = 0; w < 8; ++w) s += red[w][jj][c];
        const float g = gamma[0];
        const size_t o = (size_t)(b * NN + j0 + jj) * CC + c;
        out[o] = fmaf(g, s, x[o]);
    }
}

extern "C" void kernel_launch(void* const* d_in, const int* in_sizes, int n_in,
                              void* d_out, int out_size, void* d_ws, size_t ws_size,
                              hipStream_t stream) {
    const float* x     = (const float*)d_in[0];
    const float* gamma = (const float*)d_in[1];
    float* out = (float*)d_out;

    // ws layout: Xf16 (512 KB) | XT f16 (512 KB) | c2 fp32 (32 KB)
    _Float16* xf = (_Float16*)d_ws;
    _Float16* xt = xf + (size_t)2 * NN * CC;
    float*    c2 = (float*)(xt + (size_t)2 * CC * NN);

    k_convert<<<dim3(256), dim3(256), 0, stream>>>(x, xf, xt);
    k_pass1 <<<dim3(512), dim3(512), 0, stream>>>(xf, c2);
    k_pass2 <<<dim3(512), dim3(512), 0, stream>>>(xf, xt, c2, x, gamma, out);
}